// Round 1
// baseline (222.897 us; speedup 1.0000x reference)
//
#include <hip/hip_runtime.h>
#include <hip/hip_bf16.h>

typedef short short8 __attribute__((ext_vector_type(8)));
typedef short short4v __attribute__((ext_vector_type(4)));
typedef float f32x4 __attribute__((ext_vector_type(4)));

#define K_DIM 2048
#define N_DIM 2048
#define M_DIM 16384
#define NW 4194304   // weight element count (2048*2048)

// ---------------- w_scale: deterministic 2-stage f64 abs-mean ----------------
__global__ void k_wsum(const float4* __restrict__ w4, double* __restrict__ red) {
  const int n4 = NW / 4;
  double s = 0.0;
  for (int i = blockIdx.x * blockDim.x + threadIdx.x; i < n4; i += gridDim.x * blockDim.x) {
    float4 v = w4[i];
    s += (double)fabsf(v.x) + (double)fabsf(v.y) + (double)fabsf(v.z) + (double)fabsf(v.w);
  }
  for (int o = 32; o; o >>= 1) s += __shfl_xor(s, o);
  __shared__ double sd[4];
  if ((threadIdx.x & 63) == 0) sd[threadIdx.x >> 6] = s;
  __syncthreads();
  if (threadIdx.x == 0) red[blockIdx.x] = (sd[0] + sd[1]) + (sd[2] + sd[3]);
}

__global__ void k_wscale(const double* __restrict__ red, double* __restrict__ wsd) {
  double s = 0.0;
  for (int i = 0; i < 256; ++i) s += red[i];
  double m = s / (double)NW;
  *wsd = (m > 1e-6) ? m : 1e-6;
}

// ---------------- weight ternary quant -> bf16 {-1,0,1} ----------------
__device__ __forceinline__ unsigned short wq1(float v, double ws) {
  double r = rint((double)v / ws);          // round-half-even, matches np.round
  r = fmin(fmax(r, -1.0), 1.0);
  float f = (float)r;
  return (unsigned short)(__float_as_uint(f) >> 16);  // exact bf16 truncation
}

__global__ void k_wquant(const float4* __restrict__ w4, const double* __restrict__ wsd,
                         short4v* __restrict__ wq4) {
  int i = blockIdx.x * blockDim.x + threadIdx.x;
  if (i >= NW / 4) return;
  double ws = *wsd;
  float4 v = w4[i];
  short4v q;
  q[0] = (short)wq1(v.x, ws);
  q[1] = (short)wq1(v.y, ws);
  q[2] = (short)wq1(v.z, ws);
  q[3] = (short)wq1(v.w, ws);
  wq4[i] = q;
}

// ---------------- per-token absmax + int8-range quant -> bf16 ----------------
__device__ __forceinline__ unsigned short qbf16(float v, double rr) {
  double q = rint((double)v * rr);
  q = fmin(fmax(q, -127.0), 127.0);
  float f = (float)q;                        // integer in [-127,127]: exact in bf16
  return (unsigned short)(__float_as_uint(f) >> 16);
}

__global__ void k_xquant(const float* __restrict__ x, float* __restrict__ ascale,
                         unsigned short* __restrict__ xq) {
  const int row = blockIdx.x;
  const int t = threadIdx.x;
  const float4* xr = (const float4*)(x + (size_t)row * K_DIM);
  float4 v0 = xr[t];
  float4 v1 = xr[t + 256];
  float m = fmaxf(fmaxf(fmaxf(fabsf(v0.x), fabsf(v0.y)), fmaxf(fabsf(v0.z), fabsf(v0.w))),
                  fmaxf(fmaxf(fabsf(v1.x), fabsf(v1.y)), fmaxf(fabsf(v1.z), fabsf(v1.w))));
  for (int o = 32; o; o >>= 1) m = fmaxf(m, __shfl_xor(m, o));
  __shared__ float sm[4];
  if ((t & 63) == 0) sm[t >> 6] = m;
  __syncthreads();
  float a = fmaxf(fmaxf(sm[0], sm[1]), fmaxf(sm[2], sm[3]));
  a = fmaxf(a, 1e-8f);
  if (t == 0) ascale[row] = a;
  double rr = 127.0 / (double)a;
  short4v qa, qb;
  qa[0] = (short)qbf16(v0.x, rr);
  qa[1] = (short)qbf16(v0.y, rr);
  qa[2] = (short)qbf16(v0.z, rr);
  qa[3] = (short)qbf16(v0.w, rr);
  qb[0] = (short)qbf16(v1.x, rr);
  qb[1] = (short)qbf16(v1.y, rr);
  qb[2] = (short)qbf16(v1.z, rr);
  qb[3] = (short)qbf16(v1.w, rr);
  short4v* qr = (short4v*)(xq + (size_t)row * K_DIM);
  qr[t] = qa;
  qr[t + 256] = qb;
}

// ---------------- GEMM: y[t,o] = sum_k xq[t,k]*wq[o,k], scaled epilogue ------
#define BK 64

__device__ __forceinline__ void gload16(const void* g, void* l) {
  __builtin_amdgcn_global_load_lds(
      (const __attribute__((address_space(1))) void*)g,
      (__attribute__((address_space(3))) void*)l, 16, 0, 0);
}

__global__ __launch_bounds__(256) void k_gemm(
    const unsigned short* __restrict__ xq, const unsigned short* __restrict__ wq,
    const float* __restrict__ ascale, const double* __restrict__ wsd,
    float* __restrict__ out) {
  __shared__ __align__(16) unsigned short lA[128 * 64];
  __shared__ __align__(16) unsigned short lB[128 * 64];
  const int tid = threadIdx.x;
  const int l = tid & 63;
  const int wv = tid >> 6;
  const int wm = wv >> 1, wn = wv & 1;
  const int g = l >> 4, r16 = l & 15;
  const int bc = blockIdx.x, br = blockIdx.y;

  const char* Ab = (const char*)(xq + (size_t)br * 128 * K_DIM);
  const char* Bb = (const char*)(wq + (size_t)bc * 128 * K_DIM);

  f32x4 acc[4][4];
#pragma unroll
  for (int m = 0; m < 4; ++m)
#pragma unroll
    for (int n = 0; n < 4; ++n) acc[m][n] = (f32x4){0.f, 0.f, 0.f, 0.f};

  // staging: linear LDS dest (global_load_lds writes base + lane*16),
  // source pre-swizzled so reads can XOR-deswizzle (rule: both sides or neither)
  int soff[4], loff[4];
#pragma unroll
  for (int c = 0; c < 4; ++c) {
    int chunk = c * 4 + wv;              // 16 KiB tile = 16 x 1 KiB wave-chunks
    int lb = chunk * 1024;
    loff[c] = lb;
    int lane_b = lb + l * 16;
    int row = lane_b >> 7;               // 128 B per row (BK=64 bf16)
    int cb = lane_b & 127;
    int scb = cb ^ ((row & 7) << 4);     // involution swizzle
    soff[c] = row * (K_DIM * 2) + scb;
  }

  for (int k0 = 0; k0 < K_DIM; k0 += BK) {
#pragma unroll
    for (int c = 0; c < 4; ++c) {
      gload16(Ab + soff[c] + k0 * 2, (char*)lA + loff[c]);
      gload16(Bb + soff[c] + k0 * 2, (char*)lB + loff[c]);
    }
    asm volatile("s_waitcnt vmcnt(0)" ::: "memory");
    __syncthreads();
#pragma unroll
    for (int ks = 0; ks < 2; ++ks) {
      short8 af[4], bfr[4];
#pragma unroll
      for (int m = 0; m < 4; ++m) {
        int row = wm * 64 + m * 16 + r16;
        int b = (row << 7) + ((ks * 64 + g * 16) ^ ((row & 7) << 4));
        af[m] = *(const short8*)((const char*)lA + b);
      }
#pragma unroll
      for (int n = 0; n < 4; ++n) {
        int row = wn * 64 + n * 16 + r16;
        int b = (row << 7) + ((ks * 64 + g * 16) ^ ((row & 7) << 4));
        bfr[n] = *(const short8*)((const char*)lB + b);
      }
#pragma unroll
      for (int m = 0; m < 4; ++m)
#pragma unroll
        for (int n = 0; n < 4; ++n)
          acc[m][n] = __builtin_amdgcn_mfma_f32_16x16x32_bf16(af[m], bfr[n], acc[m][n], 0, 0, 0);
    }
    __syncthreads();
  }

  // epilogue: y = acc * w_scale * (a_scale[t]/127)
  float wsf = (float)(*wsd);
  size_t trow0 = (size_t)br * 128 + wm * 64;
  int oc0 = bc * 128 + wn * 64;
#pragma unroll
  for (int m = 0; m < 4; ++m) {
#pragma unroll
    for (int j = 0; j < 4; ++j) {
      size_t t = trow0 + m * 16 + g * 4 + j;   // C/D: col=lane&15, row=(lane>>4)*4+reg
      float s = wsf * (ascale[t] / 127.0f);
      float* yr = out + t * (size_t)N_DIM + oc0;
#pragma unroll
      for (int n = 0; n < 4; ++n) yr[n * 16 + r16] = acc[m][n][j] * s;
    }
  }
}

extern "C" void kernel_launch(void* const* d_in, const int* in_sizes, int n_in,
                              void* d_out, int out_size, void* d_ws, size_t ws_size,
                              hipStream_t stream) {
  const float* x = (const float*)d_in[0];
  const float* w = (const float*)d_in[1];
  float* out = (float*)d_out;

  char* ws = (char*)d_ws;
  double* red = (double*)ws;                               // 256 * 8 B
  double* wsd = (double*)(ws + 2048);                      // 1 double
  float* ascale = (float*)(ws + 4096);                     // 16384 floats
  unsigned short* xq = (unsigned short*)(ws + 4096 + 65536);                 // 64 MiB
  unsigned short* wq = (unsigned short*)(ws + 4096 + 65536 + (size_t)M_DIM * K_DIM * 2);  // 8 MiB

  k_wsum<<<256, 256, 0, stream>>>((const float4*)w, red);
  k_wscale<<<1, 1, 0, stream>>>(red, wsd);
  k_wquant<<<NW / 4 / 256, 256, 0, stream>>>((const float4*)w, wsd, (short4v*)wq);
  k_xquant<<<M_DIM, 256, 0, stream>>>(x, ascale, xq);
  k_gemm<<<dim3(N_DIM / 128, M_DIM / 128), 256, 0, stream>>>(xq, wq, ascale, wsd, out);
}

// Round 2
// 151.514 us; speedup vs baseline: 1.4711x; 1.4711x over previous
//
#include <hip/hip_runtime.h>
#include <hip/hip_bf16.h>

typedef float f32x4 __attribute__((ext_vector_type(4)));
typedef int int4v __attribute__((ext_vector_type(4)));
typedef char char8 __attribute__((ext_vector_type(8)));

#define K_DIM 2048
#define N_DIM 2048
#define M_DIM 16384
#define NW 4194304   // weight element count (2048*2048)

// ---------------- w_scale: deterministic 2-stage f64 abs-mean ----------------
__global__ void k_wsum(const float4* __restrict__ w4, double* __restrict__ red) {
  const int n4 = NW / 4;
  double s = 0.0;
  for (int i = blockIdx.x * blockDim.x + threadIdx.x; i < n4; i += gridDim.x * blockDim.x) {
    float4 v = w4[i];
    s += (double)fabsf(v.x) + (double)fabsf(v.y) + (double)fabsf(v.z) + (double)fabsf(v.w);
  }
  for (int o = 32; o; o >>= 1) s += __shfl_xor(s, o);
  __shared__ double sd[4];
  if ((threadIdx.x & 63) == 0) sd[threadIdx.x >> 6] = s;
  __syncthreads();
  if (threadIdx.x == 0) red[blockIdx.x] = (sd[0] + sd[1]) + (sd[2] + sd[3]);
}

__global__ void k_wscale(const double* __restrict__ red, double* __restrict__ wsd) {
  double s = 0.0;
  for (int i = 0; i < 256; ++i) s += red[i];
  double m = s / (double)NW;
  *wsd = (m > 1e-6) ? m : 1e-6;
}

// ---------------- weight ternary quant -> int8 {-1,0,1} ----------------
__device__ __forceinline__ char wq1(float v, double ws) {
  double r = rint((double)v / ws);          // round-half-even, matches np.round
  r = fmin(fmax(r, -1.0), 1.0);
  return (char)(int)r;
}

__global__ void k_wquant(const float4* __restrict__ w4, const double* __restrict__ wsd,
                         char4* __restrict__ wq4) {
  int i = blockIdx.x * blockDim.x + threadIdx.x;
  if (i >= NW / 4) return;
  double ws = *wsd;
  float4 v = w4[i];
  char4 q;
  q.x = wq1(v.x, ws);
  q.y = wq1(v.y, ws);
  q.z = wq1(v.z, ws);
  q.w = wq1(v.w, ws);
  wq4[i] = q;
}

// ---------------- per-token absmax + int8 absmax quant ----------------
__device__ __forceinline__ char qi8(float v, double rr) {
  double q = rint((double)v * rr);
  q = fmin(fmax(q, -127.0), 127.0);
  return (char)(int)q;
}

__global__ void k_xquant(const float* __restrict__ x, float* __restrict__ ascale,
                         char* __restrict__ xq) {
  const int row = blockIdx.x;
  const int t = threadIdx.x;
  const float4* xr = (const float4*)(x + (size_t)row * K_DIM);
  float4 v0 = xr[t];
  float4 v1 = xr[t + 256];
  float m = fmaxf(fmaxf(fmaxf(fabsf(v0.x), fabsf(v0.y)), fmaxf(fabsf(v0.z), fabsf(v0.w))),
                  fmaxf(fmaxf(fabsf(v1.x), fabsf(v1.y)), fmaxf(fabsf(v1.z), fabsf(v1.w))));
  for (int o = 32; o; o >>= 1) m = fmaxf(m, __shfl_xor(m, o));
  __shared__ float sm[4];
  if ((t & 63) == 0) sm[t >> 6] = m;
  __syncthreads();
  float a = fmaxf(fmaxf(sm[0], sm[1]), fmaxf(sm[2], sm[3]));
  a = fmaxf(a, 1e-8f);
  if (t == 0) ascale[row] = a;
  double rr = 127.0 / (double)a;
  char8 q;
  q[0] = qi8(v0.x, rr); q[1] = qi8(v0.y, rr); q[2] = qi8(v0.z, rr); q[3] = qi8(v0.w, rr);
  q[4] = qi8(v1.x, rr); q[5] = qi8(v1.y, rr); q[6] = qi8(v1.z, rr); q[7] = qi8(v1.w, rr);
  // layout: thread t covers elems [4t..4t+3] and [1024+4t..1024+4t+3]
  char8* qr = (char8*)(xq + (size_t)row * K_DIM);
  char8 lo, hi;
  lo[0]=q[0]; lo[1]=q[1]; lo[2]=q[2]; lo[3]=q[3];
  // need two 4B stores at t*4 and 1024+t*4; do them as char4 stores
  char4* qr4 = (char4*)(xq + (size_t)row * K_DIM);
  char4 a4, b4;
  a4.x=q[0]; a4.y=q[1]; a4.z=q[2]; a4.w=q[3];
  b4.x=q[4]; b4.y=q[5]; b4.z=q[6]; b4.w=q[7];
  qr4[t] = a4;
  qr4[t + 256] = b4;
  (void)qr; (void)lo; (void)hi;
}

// ---------------- GEMM: y[t,o] = sum_k xq[t,k]*wq[o,k], i8 MFMA, scaled epilogue
#define BK 128   // i8 elements per K-step; 128 B per LDS row (same byte geometry as before)

__device__ __forceinline__ void gload16(const void* g, void* l) {
  __builtin_amdgcn_global_load_lds(
      (const __attribute__((address_space(1))) void*)g,
      (__attribute__((address_space(3))) void*)l, 16, 0, 0);
}

__global__ __launch_bounds__(256) void k_gemm(
    const char* __restrict__ xq, const char* __restrict__ wq,
    const float* __restrict__ ascale, const double* __restrict__ wsd,
    float* __restrict__ out) {
  __shared__ __align__(16) char lA[128 * BK];   // 16 KiB
  __shared__ __align__(16) char lB[128 * BK];   // 16 KiB
  const int tid = threadIdx.x;
  const int l = tid & 63;
  const int wv = tid >> 6;
  const int wm = wv >> 1, wn = wv & 1;
  const int g = l >> 4, r16 = l & 15;
  const int bc = blockIdx.x, br = blockIdx.y;

  const char* Ab = xq + (size_t)br * 128 * K_DIM;
  const char* Bb = wq + (size_t)bc * 128 * K_DIM;

  int4v acc[4][4];
#pragma unroll
  for (int m = 0; m < 4; ++m)
#pragma unroll
    for (int n = 0; n < 4; ++n) acc[m][n] = (int4v){0, 0, 0, 0};

  // staging: linear LDS dest (global_load_lds writes base + lane*16),
  // source pre-swizzled so reads XOR-deswizzle (both-sides-or-neither rule)
  int soff[4], loff[4];
#pragma unroll
  for (int c = 0; c < 4; ++c) {
    int chunk = c * 4 + wv;              // 16 KiB tile = 16 x 1 KiB wave-chunks
    int lb = chunk * 1024;
    loff[c] = lb;
    int lane_b = lb + l * 16;
    int row = lane_b >> 7;               // 128 B per row (BK=128 i8)
    int cb = lane_b & 127;
    int scb = cb ^ ((row & 7) << 4);     // involution swizzle
    soff[c] = row * K_DIM + scb;         // global row stride = K_DIM bytes
  }

  for (int k0 = 0; k0 < K_DIM; k0 += BK) {
#pragma unroll
    for (int c = 0; c < 4; ++c) {
      gload16(Ab + soff[c] + k0, lA + loff[c]);
      gload16(Bb + soff[c] + k0, lB + loff[c]);
    }
    asm volatile("s_waitcnt vmcnt(0)" ::: "memory");
    __syncthreads();
#pragma unroll
    for (int ks = 0; ks < 2; ++ks) {
      int4v af[4], bfr[4];
#pragma unroll
      for (int m = 0; m < 4; ++m) {
        int row = wm * 64 + m * 16 + r16;
        int b = (row << 7) + ((ks * 64 + g * 16) ^ ((row & 7) << 4));
        af[m] = *(const int4v*)(lA + b);
      }
#pragma unroll
      for (int n = 0; n < 4; ++n) {
        int row = wn * 64 + n * 16 + r16;
        int b = (row << 7) + ((ks * 64 + g * 16) ^ ((row & 7) << 4));
        bfr[n] = *(const int4v*)(lB + b);
      }
#pragma unroll
      for (int m = 0; m < 4; ++m)
#pragma unroll
        for (int n = 0; n < 4; ++n)
          acc[m][n] = __builtin_amdgcn_mfma_i32_16x16x64_i8(af[m], bfr[n], acc[m][n], 0, 0, 0);
    }
    __syncthreads();
  }

  // epilogue: y = acc * w_scale * (a_scale[t]/127); |acc| <= 127*2048 < 2^24 -> exact
  float wsf = (float)(*wsd);
  size_t trow0 = (size_t)br * 128 + wm * 64;
  int oc0 = bc * 128 + wn * 64;
#pragma unroll
  for (int m = 0; m < 4; ++m) {
#pragma unroll
    for (int j = 0; j < 4; ++j) {
      size_t t = trow0 + m * 16 + g * 4 + j;   // C/D: col=lane&15, row=(lane>>4)*4+reg
      float s = wsf * (ascale[t] / 127.0f);
      float* yr = out + t * (size_t)N_DIM + oc0;
#pragma unroll
      for (int n = 0; n < 4; ++n) yr[n * 16 + r16] = (float)acc[m][n][j] * s;
    }
  }
}

extern "C" void kernel_launch(void* const* d_in, const int* in_sizes, int n_in,
                              void* d_out, int out_size, void* d_ws, size_t ws_size,
                              hipStream_t stream) {
  const float* x = (const float*)d_in[0];
  const float* w = (const float*)d_in[1];
  float* out = (float*)d_out;

  char* ws = (char*)d_ws;
  double* red = (double*)ws;                               // 256 * 8 B
  double* wsd = (double*)(ws + 2048);                      // 1 double
  float* ascale = (float*)(ws + 4096);                     // 16384 floats
  char* xq = (char*)(ws + 4096 + 65536);                   // 32 MiB
  char* wq = xq + (size_t)M_DIM * K_DIM;                   // 4 MiB

  k_wsum<<<256, 256, 0, stream>>>((const float4*)w, red);
  k_wscale<<<1, 1, 0, stream>>>(red, wsd);
  k_wquant<<<NW / 4 / 256, 256, 0, stream>>>((const float4*)w, wsd, (char4*)wq);
  k_xquant<<<M_DIM, 256, 0, stream>>>(x, ascale, xq);
  k_gemm<<<dim3(N_DIM / 128, M_DIM / 128), 256, 0, stream>>>(xq, wq, ascale, wsd, out);
}

// Round 3
// 131.239 us; speedup vs baseline: 1.6984x; 1.1545x over previous
//
#include <hip/hip_runtime.h>
#include <hip/hip_bf16.h>

typedef int int4v __attribute__((ext_vector_type(4)));

#define K_DIM 2048
#define N_DIM 2048
#define M_DIM 16384
#define NW 4194304   // weight element count (2048*2048)
#define BKB 128      // K-step bytes per row (128 i8 elements)
#define NKT (K_DIM / BKB)   // 16 K-tiles

// ---------------- w_scale: deterministic 2-stage f64 abs-mean ----------------
__global__ void k_wsum(const float4* __restrict__ w4, double* __restrict__ red) {
  const int n4 = NW / 4;
  double s = 0.0;
  for (int i = blockIdx.x * blockDim.x + threadIdx.x; i < n4; i += gridDim.x * blockDim.x) {
    float4 v = w4[i];
    s += (double)fabsf(v.x) + (double)fabsf(v.y) + (double)fabsf(v.z) + (double)fabsf(v.w);
  }
  for (int o = 32; o; o >>= 1) s += __shfl_xor(s, o);
  __shared__ double sd[4];
  if ((threadIdx.x & 63) == 0) sd[threadIdx.x >> 6] = s;
  __syncthreads();
  if (threadIdx.x == 0) red[blockIdx.x] = (sd[0] + sd[1]) + (sd[2] + sd[3]);
}

__global__ void k_wscale(const double* __restrict__ red, double* __restrict__ wsd) {
  double s = 0.0;
  for (int i = 0; i < 256; ++i) s += red[i];
  double m = s / (double)NW;
  *wsd = (m > 1e-6) ? m : 1e-6;
}

// ---------------- weight ternary quant -> int8 {-1,0,1} ----------------
__device__ __forceinline__ char wq1(float v, double ws) {
  double r = rint((double)v / ws);          // round-half-even, matches np.round
  r = fmin(fmax(r, -1.0), 1.0);
  return (char)(int)r;
}

__global__ void k_wquant(const float4* __restrict__ w4, const double* __restrict__ wsd,
                         char4* __restrict__ wq4) {
  int i = blockIdx.x * blockDim.x + threadIdx.x;
  if (i >= NW / 4) return;
  double ws = *wsd;
  float4 v = w4[i];
  char4 q;
  q.x = wq1(v.x, ws);
  q.y = wq1(v.y, ws);
  q.z = wq1(v.z, ws);
  q.w = wq1(v.w, ws);
  wq4[i] = q;
}

// ---------------- per-token absmax + int8 absmax quant ----------------
__device__ __forceinline__ char qi8(float v, double rr) {
  double q = rint((double)v * rr);
  q = fmin(fmax(q, -127.0), 127.0);
  return (char)(int)q;
}

__global__ void k_xquant(const float* __restrict__ x, float* __restrict__ ascale,
                         char* __restrict__ xq) {
  const int row = blockIdx.x;
  const int t = threadIdx.x;
  const float4* xr = (const float4*)(x + (size_t)row * K_DIM);
  float4 v0 = xr[t];
  float4 v1 = xr[t + 256];
  float m = fmaxf(fmaxf(fmaxf(fabsf(v0.x), fabsf(v0.y)), fmaxf(fabsf(v0.z), fabsf(v0.w))),
                  fmaxf(fmaxf(fabsf(v1.x), fabsf(v1.y)), fmaxf(fabsf(v1.z), fabsf(v1.w))));
  for (int o = 32; o; o >>= 1) m = fmaxf(m, __shfl_xor(m, o));
  __shared__ float sm[4];
  if ((t & 63) == 0) sm[t >> 6] = m;
  __syncthreads();
  float a = fmaxf(fmaxf(sm[0], sm[1]), fmaxf(sm[2], sm[3]));
  a = fmaxf(a, 1e-8f);
  if (t == 0) ascale[row] = a;
  double rr = 127.0 / (double)a;
  char4* qr4 = (char4*)(xq + (size_t)row * K_DIM);
  char4 a4, b4;
  a4.x = qi8(v0.x, rr); a4.y = qi8(v0.y, rr); a4.z = qi8(v0.z, rr); a4.w = qi8(v0.w, rr);
  b4.x = qi8(v1.x, rr); b4.y = qi8(v1.y, rr); b4.z = qi8(v1.z, rr); b4.w = qi8(v1.w, rr);
  qr4[t] = a4;
  qr4[t + 256] = b4;
}

// ---------------- GEMM: 256x256 tile, 8 waves, counted-vmcnt 4-phase pipeline
__device__ __forceinline__ void gload16(const void* g, void* l) {
  __builtin_amdgcn_global_load_lds(
      (const __attribute__((address_space(1))) void*)g,
      (__attribute__((address_space(3))) void*)l, 16, 0, 0);
}

#define STAGE2(SRC, DST, C0, C1)              \
  gload16((SRC) + soff[C0], (DST) + loff[C0]); \
  gload16((SRC) + soff[C1], (DST) + loff[C1]);

#define READ_A(MH, CO)                                        \
  _Pragma("unroll") for (int mf = 0; mf < 4; ++mf) {          \
    int row = rA + (MH)*64 + mf * 16;                         \
    af[mf] = *(const int4v*)(cA + row * 128 + (CO));          \
  }

#define READ_B(CO)                                            \
  _Pragma("unroll") for (int nf = 0; nf < 4; ++nf) {          \
    int row = rB + nf * 16;                                   \
    bfr[nf] = *(const int4v*)(cB + row * 128 + (CO));         \
  }

#define MFMA16(MH)                                                             \
  __builtin_amdgcn_s_setprio(1);                                               \
  _Pragma("unroll") for (int mf = 0; mf < 4; ++mf)                             \
  _Pragma("unroll") for (int nf = 0; nf < 4; ++nf)                             \
    acc[(MH)*4 + mf][nf] = __builtin_amdgcn_mfma_i32_16x16x64_i8(              \
        af[mf], bfr[nf], acc[(MH)*4 + mf][nf], 0, 0, 0);                       \
  __builtin_amdgcn_s_setprio(0);

#define FENCE_LGKM0                                          \
  asm volatile("s_waitcnt lgkmcnt(0)" ::: "memory");         \
  __builtin_amdgcn_sched_barrier(0);

__global__ __launch_bounds__(512, 2) void k_gemm(
    const char* __restrict__ xq, const char* __restrict__ wq,
    const float* __restrict__ ascale, const double* __restrict__ wsd,
    float* __restrict__ out) {
  __shared__ __align__(16) char lds[131072];
  char* lA0 = lds;            // 32 KB A buf 0
  char* lB0 = lds + 32768;    // 32 KB B buf 0
  char* lA1 = lds + 65536;
  char* lB1 = lds + 98304;

  const int tid = threadIdx.x;
  const int l = tid & 63;
  const int wv = tid >> 6;        // 0..7
  const int wm = wv >> 2;         // M half
  const int wn = wv & 3;          // N quarter
  const int g = l >> 4, r16 = l & 15;

  // XCD-aware bijective swizzle: 512 blocks = 8 xcd * 64 chunk
  const int bid = blockIdx.x;
  const int logical = (bid & 7) * 64 + (bid >> 3);
  const int br = logical >> 3;    // 0..63  (M blocks)
  const int bc = logical & 7;     // 0..7   (N blocks)

  const char* Ab = xq + (size_t)br * 256 * K_DIM;
  const char* Bb = wq + (size_t)bc * 256 * K_DIM;

  // staging geometry: operand tile = 256 rows x 128 B = 32 KB = 4 chunks of 8 KB
  // LDS dest linear (global_load_lds constraint); source pre-swizzled (involution)
  int soff[4], loff[4];
#pragma unroll
  for (int c = 0; c < 4; ++c) {
    int lb = c * 8192 + tid * 16;
    loff[c] = lb;
    int row = lb >> 7;
    int cb = lb & 127;
    soff[c] = row * K_DIM + (cb ^ ((row & 7) << 4));
  }

  // read-side swizzled column offsets (row&7 == r16&7 for all fragment rows)
  const int sw = (r16 & 7) << 4;
  const int co0 = (g * 16) ^ sw;        // k-slice 0
  const int co1 = (64 + g * 16) ^ sw;   // k-slice 1
  const int rA = wm * 128 + r16;
  const int rB = wn * 64 + r16;

  int4v acc[8][4];
#pragma unroll
  for (int mf = 0; mf < 8; ++mf)
#pragma unroll
    for (int nf = 0; nf < 4; ++nf) acc[mf][nf] = (int4v){0, 0, 0, 0};

  // prologue: stage tile 0 into buf0 (8 loads/thread)
#pragma unroll
  for (int c = 0; c < 4; ++c) gload16(Ab + soff[c], lA0 + loff[c]);
#pragma unroll
  for (int c = 0; c < 4; ++c) gload16(Bb + soff[c], lB0 + loff[c]);

  char* cA = lA0; char* cB = lB0;
  char* nA = lA1; char* nB = lB1;

  for (int kt = 0; kt < NKT; ++kt) {
    const int kn = ((kt + 1) & (NKT - 1)) * BKB;  // wrap keeps counts uniform
    const char* An = Ab + kn;
    const char* Bn = Bb + kn;
    int4v af[4], bfr[4];

    // ---- phase 0: stage A c0,c1 | gate on prev tile | quadrant (mh0, ks0)
    STAGE2(An, nA, 0, 1);
    asm volatile("s_waitcnt vmcnt(2)" ::: "memory");  // prev tile's 8 landed
    __builtin_amdgcn_s_barrier();
    asm volatile("" ::: "memory");
    READ_A(0, co0);
    READ_B(co0);
    FENCE_LGKM0;
    MFMA16(0);

    // ---- phase 1: stage A c2,c3 | quadrant (mh1, ks0), reuse B frags
    STAGE2(An, nA, 2, 3);
    READ_A(1, co0);
    FENCE_LGKM0;
    MFMA16(1);

    // ---- phase 2: stage B c0,c1 | quadrant (mh0, ks1)
    STAGE2(Bn, nB, 0, 1);
    READ_A(0, co1);
    READ_B(co1);
    FENCE_LGKM0;
    MFMA16(0);

    // ---- phase 3: stage B c2,c3 | quadrant (mh1, ks1)
    STAGE2(Bn, nB, 2, 3);
    READ_A(1, co1);
    FENCE_LGKM0;
    MFMA16(1);

    // all reads of cA/cB done -> safe for next iter to overwrite them
    asm volatile("" ::: "memory");
    __builtin_amdgcn_s_barrier();
    asm volatile("" ::: "memory");

    char* t;
    t = cA; cA = nA; nA = t;
    t = cB; cB = nB; nB = t;
  }

  // epilogue: y = acc * w_scale * (a_scale[t]/127); |acc| <= 127*2048 < 2^24 exact
  float wsf = (float)(*wsd);
  size_t trow0 = (size_t)br * 256 + wm * 128;
  int oc0 = bc * 256 + wn * 64;
#pragma unroll
  for (int mf = 0; mf < 8; ++mf) {
#pragma unroll
    for (int j = 0; j < 4; ++j) {
      size_t t = trow0 + mf * 16 + g * 4 + j;  // C/D: col=lane&15, row=(lane>>4)*4+reg
      float s = wsf * (ascale[t] / 127.0f);
      float* yr = out + t * (size_t)N_DIM + oc0;
#pragma unroll
      for (int nf = 0; nf < 4; ++nf) yr[nf * 16 + r16] = (float)acc[mf][nf][j] * s;
    }
  }
}

extern "C" void kernel_launch(void* const* d_in, const int* in_sizes, int n_in,
                              void* d_out, int out_size, void* d_ws, size_t ws_size,
                              hipStream_t stream) {
  const float* x = (const float*)d_in[0];
  const float* w = (const float*)d_in[1];
  float* out = (float*)d_out;

  char* ws = (char*)d_ws;
  double* red = (double*)ws;                               // 256 * 8 B
  double* wsd = (double*)(ws + 2048);                      // 1 double
  float* ascale = (float*)(ws + 4096);                     // 16384 floats
  char* xq = (char*)(ws + 4096 + 65536);                   // 32 MiB
  char* wq = xq + (size_t)M_DIM * K_DIM;                   // 4 MiB

  k_wsum<<<256, 256, 0, stream>>>((const float4*)w, red);
  k_wscale<<<1, 1, 0, stream>>>(red, wsd);
  k_wquant<<<NW / 4 / 256, 256, 0, stream>>>((const float4*)w, wsd, (char4*)wq);
  k_xquant<<<M_DIM, 256, 0, stream>>>(x, ascale, xq);
  k_gemm<<<dim3(N_DIM / 256 * M_DIM / 256), 512, 0, stream>>>(xq, wq, ascale, wsd, out);
}